// Round 6
// baseline (257.059 us; speedup 1.0000x reference)
//
#include <hip/hip_runtime.h>
#include <hip/hip_bf16.h>
#include <math.h>

// Problem constants
#define BS 32
#define SEQ 50
#define ML 16
#define NN 15
#define NTREE (BS*SEQ*ML)     // 25600
#define NROW (BS*SEQ)         // 1600
#define VOCAB 50000
#define EMB 128
#define ENC 128
#define GH 32
#define NC 100
#define LH 128
#define LIN_D 167             // 101 + 64 + 2

typedef float f32x4 __attribute__((ext_vector_type(4)));

// ---------------------------------------------------------------------------
// fp32 GEMM: C[M][N] = A[M][K] @ B[N][K]^T (+ bias[N])
// BM=64 x BN=128 tile, BK=32, 256 threads, 4x8 per thread.
// ---------------------------------------------------------------------------
__global__ __launch_bounds__(256) void sgemm_nt(const float* __restrict__ A,
    const float* __restrict__ B, const float* __restrict__ bias,
    float* __restrict__ C, int M, int N, int K) {
  __shared__ float As[32][68];    // [k][m]
  __shared__ float Bs[32][132];   // [k][n]
  const int bm = blockIdx.y * 64, bn = blockIdx.x * 128;
  const int tid = threadIdx.x;
  const int tm = (tid >> 4) << 2;   // 0..60
  const int tn = (tid & 15) << 3;   // 0..120
  const int srow = tid >> 3;        // 0..31
  const int q4 = (tid & 7) << 2;    // 0,4,..,28
  const bool vec_ok = ((K & 3) == 0);

  float acc[4][8];
  #pragma unroll
  for (int i = 0; i < 4; i++)
    #pragma unroll
    for (int j = 0; j < 8; j++) acc[i][j] = 0.f;

  for (int k0 = 0; k0 < K; k0 += 32) {
    if (vec_ok && (k0 + 32 <= K)) {
      #pragma unroll
      for (int h = 0; h < 2; h++) {
        int gm = bm + srow + h * 32;
        int rm = (gm < M) ? gm : (M - 1);
        float4 av = *(const float4*)&A[(size_t)rm * K + k0 + q4];
        As[q4 + 0][srow + h * 32] = av.x;
        As[q4 + 1][srow + h * 32] = av.y;
        As[q4 + 2][srow + h * 32] = av.z;
        As[q4 + 3][srow + h * 32] = av.w;
      }
      #pragma unroll
      for (int h = 0; h < 4; h++) {
        int gn = bn + srow + h * 32;
        float4 bv = make_float4(0.f, 0.f, 0.f, 0.f);
        if (gn < N) bv = *(const float4*)&B[(size_t)gn * K + k0 + q4];
        Bs[q4 + 0][srow + h * 32] = bv.x;
        Bs[q4 + 1][srow + h * 32] = bv.y;
        Bs[q4 + 2][srow + h * 32] = bv.z;
        Bs[q4 + 3][srow + h * 32] = bv.w;
      }
    } else {
      #pragma unroll
      for (int h = 0; h < 2; h++) {
        int gm = bm + srow + h * 32;
        int rm = (gm < M) ? gm : (M - 1);
        #pragma unroll
        for (int j = 0; j < 4; j++) {
          int gk = k0 + q4 + j;
          As[q4 + j][srow + h * 32] = (gk < K) ? A[(size_t)rm * K + gk] : 0.f;
        }
      }
      #pragma unroll
      for (int h = 0; h < 4; h++) {
        int gn = bn + srow + h * 32;
        #pragma unroll
        for (int j = 0; j < 4; j++) {
          int gk = k0 + q4 + j;
          Bs[q4 + j][srow + h * 32] =
              (gn < N && gk < K) ? B[(size_t)gn * K + gk] : 0.f;
        }
      }
    }
    __syncthreads();
    #pragma unroll
    for (int kk = 0; kk < 32; kk++) {
      float4 a4 = *(const float4*)&As[kk][tm];
      float4 b0 = *(const float4*)&Bs[kk][tn];
      float4 b1 = *(const float4*)&Bs[kk][tn + 4];
      float a[4] = {a4.x, a4.y, a4.z, a4.w};
      float b[8] = {b0.x, b0.y, b0.z, b0.w, b1.x, b1.y, b1.z, b1.w};
      #pragma unroll
      for (int i = 0; i < 4; i++)
        #pragma unroll
        for (int j = 0; j < 8; j++) acc[i][j] += a[i] * b[j];
    }
    __syncthreads();
  }

  float bb[8];
  #pragma unroll
  for (int j = 0; j < 8; j++) {
    int gn = bn + tn + j;
    bb[j] = (bias && gn < N) ? bias[gn] : 0.f;
  }
  if (bn + tn < N) {
    #pragma unroll
    for (int i = 0; i < 4; i++) {
      int gm = bm + tm + i;
      if (gm >= M) continue;
      float4 v0 = make_float4(acc[i][0] + bb[0], acc[i][1] + bb[1],
                              acc[i][2] + bb[2], acc[i][3] + bb[3]);
      float4 v1 = make_float4(acc[i][4] + bb[4], acc[i][5] + bb[5],
                              acc[i][6] + bb[6], acc[i][7] + bb[7]);
      *(float4*)&C[(size_t)gm * N + bn + tn] = v0;
      *(float4*)&C[(size_t)gm * N + bn + tn + 4] = v1;
    }
  }
}

// ---------------------------------------------------------------------------
// Prep: Wall = [WxF; WxB] (192x128), ball = [bxF; bxB]
// ---------------------------------------------------------------------------
__global__ __launch_bounds__(256) void k_prep(const float* __restrict__ WxF,
    const float* __restrict__ WxB, const float* __restrict__ bxF,
    const float* __restrict__ bxB,
    float* __restrict__ Wall, float* __restrict__ ball) {
  int i = blockIdx.x * 256 + threadIdx.x;
  if (i < 96 * 128) Wall[i] = WxF[i];
  else if (i < 192 * 128) Wall[i] = WxB[i - 96 * 128];
  if (i < 96) ball[i] = bxF[i];
  else if (i < 192) ball[i] = bxB[i - 96];
}

// ---------------------------------------------------------------------------
// Tree: gather 15 rows of E', bottom-up subtree sums, node max. 2 trees/block.
// ---------------------------------------------------------------------------
__global__ __launch_bounds__(256) void k_tree(const int* __restrict__ ast,
    const float* __restrict__ Ep, const float* __restrict__ Wc_b,
    float* __restrict__ x) {
  int lt = threadIdx.x >> 7;      // 0/1
  int d  = threadIdx.x & 127;
  int tree = blockIdx.x * 2 + lt;
  __shared__ int toks[2][15];
  if (d < 15) toks[lt][d] = ast[(size_t)tree * 15 + d];
  __syncthreads();
  float e[15];
  #pragma unroll
  for (int n = 0; n < 15; n++) e[n] = Ep[(size_t)toks[lt][n] * 128 + d];
  float b = Wc_b[d];
  float s3 = e[3] + e[7] + e[8],  s4 = e[4] + e[9] + e[10];
  float s5 = e[5] + e[11] + e[12], s6 = e[6] + e[13] + e[14];
  float s1 = e[1] + s3 + s4, s2 = e[2] + s5 + s6;
  float s0 = e[0] + s1 + s2;
  float ml = fmaxf(fmaxf(fmaxf(e[7], e[8]), fmaxf(e[9], e[10])),
                   fmaxf(fmaxf(e[11], e[12]), fmaxf(e[13], e[14]))) + b;
  float mm = fmaxf(fmaxf(s3, s4), fmaxf(s5, s6)) + 3.f * b;
  float mt = fmaxf(s1, s2) + 7.f * b;
  float m = fmaxf(fmaxf(ml, mm), fmaxf(mt, s0 + 15.f * b));
  x[(size_t)tree * 128 + d] = m;
}

// ---------------------------------------------------------------------------
// GRU recurrence, one block per (sequence, direction). Hidden=32, gates=96.
// ---------------------------------------------------------------------------
__global__ __launch_bounds__(128) void k_gru(const float* __restrict__ xe_all,
    const float* __restrict__ WhF, const float* __restrict__ WhB,
    const float* __restrict__ bhF, const float* __restrict__ bhB,
    float* __restrict__ code) {
  int bsq = blockIdx.x >> 1, dir = blockIdx.x & 1;
  int g = threadIdx.x;
  __shared__ float whs[96 * 32];
  __shared__ float h_lds[32];
  __shared__ float rz[64];
  __shared__ float nn[32];
  const float* Wh = dir ? WhB : WhF;
  const float* bh = dir ? bhB : bhF;
  for (int i = g; i < 96 * 32; i += 128) whs[i] = Wh[i];
  if (g < 32) h_lds[g] = 0.f;
  __syncthreads();
  float w[32]; float bhv = 0.f, mxv = -1e30f;
  if (g < 96) {
    #pragma unroll
    for (int j = 0; j < 32; j++) w[j] = whs[g * 32 + j];
    bhv = bh[g];
  }
  for (int s = 0; s < 16; s++) {
    int t = dir ? (15 - s) : s;
    const float* xe = xe_all + ((size_t)(bsq * 16 + t)) * 192 + dir * 96;
    float gh = bhv, xv = 0.f;
    if (g < 96) {
      xv = xe[g];
      #pragma unroll
      for (int j = 0; j < 32; j++) gh += w[j] * h_lds[j];
    }
    if (g < 64) rz[g] = 1.f / (1.f + expf(-(xv + gh)));
    __syncthreads();
    if (g >= 64 && g < 96) nn[g - 64] = tanhf(xv + rz[g - 64] * gh);
    __syncthreads();
    if (g < 32) {
      float z = rz[g + 32];
      float hn = (1.f - z) * nn[g] + z * h_lds[g];
      mxv = fmaxf(mxv, hn);
      h_lds[g] = hn;
    }
    __syncthreads();
  }
  if (g < 32) code[(size_t)bsq * 64 + dir * 32 + g] = mxv;
}

// ---------------------------------------------------------------------------
// Build lin = [c_embed(101) | code(64) | cur_result(2)]
// ---------------------------------------------------------------------------
__global__ __launch_bounds__(256) void k_lin(const float* __restrict__ c_embed,
    const float* __restrict__ code, const float* __restrict__ cur,
    float* __restrict__ lin) {
  int i = blockIdx.x * 256 + threadIdx.x;
  if (i >= NROW * LIN_D) return;
  int row = i / LIN_D, j = i - row * LIN_D;
  float v;
  if (j < 101) v = c_embed[row * 101 + j];
  else if (j < 165) v = code[row * 64 + (j - 101)];
  else v = cur[row * 2 + (j - 165)];
  lin[i] = v;
}

// ---------------------------------------------------------------------------
// LSTM v5: 32 blocks x 1024 threads (16 waves, 4/SIMD, 128-VGPR cap).
// Thread (g = t&511, half = t>>9) owns HALF a gate row: 64 weights =
// 16 float4 = 64 VGPR, asm-pinned. Per step: 64 readlane + 64 FMA per
// thread, two LDS partial arrays, 2 barriers. Small footprint -> no spill.
// ---------------------------------------------------------------------------
#define RL(v, l) __int_as_float(__builtin_amdgcn_readlane(__float_as_int(v), (l)))

__global__ __launch_bounds__(1024, 4) void k_lstm(const float* __restrict__ xeL,
    const float* __restrict__ Wh, const float* __restrict__ bh,
    float* __restrict__ lout) {
  int b = blockIdx.x; int t = threadIdx.x;
  int lane = t & 63;
  int g = t & 511;          // gate row
  int half = t >> 9;        // 0 or 1 (uniform per wave)
  __shared__ float hbuf[128];
  __shared__ float pa[512];   // half-0 partials (incl xe + bias)
  __shared__ float pb[512];   // half-1 partials
  // --- asm-pinned load of this thread's 64 weights (16 quads = 64 VGPR) ---
  f32x4 w[16];
  const float* base = Wh + (size_t)g * 128 + half * 64;
  #pragma unroll
  for (int j = 0; j < 4; j++) {
    asm volatile("global_load_dwordx4 %0, %1, off offset:%2"
                 : "=v"(w[4*j+0]) : "v"(base), "i"(j*64+0));
    asm volatile("global_load_dwordx4 %0, %1, off offset:%2"
                 : "=v"(w[4*j+1]) : "v"(base), "i"(j*64+16));
    asm volatile("global_load_dwordx4 %0, %1, off offset:%2"
                 : "=v"(w[4*j+2]) : "v"(base), "i"(j*64+32));
    asm volatile("global_load_dwordx4 %0, %1, off offset:%2"
                 : "=v"(w[4*j+3]) : "v"(base), "i"(j*64+48));
  }
  asm volatile("s_waitcnt vmcnt(0)" ::: "memory");
  __builtin_amdgcn_sched_barrier(0);

  float bhv = (half == 0) ? bh[g] : 0.f;
  float c = 0.f;
  if (t < 128) hbuf[t] = 0.f;
  const float* xrow = xeL + (size_t)b * 50 * 512;
  float xe = (half == 0) ? xrow[g] : 0.f;   // step-0 prefetch
  __syncthreads();
  for (int step = 0; step < 50; step++) {
    float h0 = hbuf[half * 64 + lane];
    float acc_a = xe + bhv, acc_b = 0.f;
    if (half == 0 && step < 49) xe = xrow[(size_t)(step + 1) * 512 + g];
    #pragma unroll
    for (int i = 0; i < 16; i++) {
      f32x4 a = w[i];
      acc_a += RL(h0, 4*i+0) * a.x;
      acc_b += RL(h0, 4*i+1) * a.y;
      acc_a += RL(h0, 4*i+2) * a.z;
      acc_b += RL(h0, 4*i+3) * a.w;
    }
    if (half == 0) pa[g] = acc_a + acc_b;
    else           pb[g] = acc_a + acc_b;
    __syncthreads();
    if (t < 128) {
      float iv = 1.f / (1.f + expf(-(pa[t] + pb[t])));
      float fv = 1.f / (1.f + expf(-(pa[t + 128] + pb[t + 128])));
      float gv = tanhf(pa[t + 256] + pb[t + 256]);
      float ov = 1.f / (1.f + expf(-(pa[t + 384] + pb[t + 384])));
      c = fv * c + iv * gv;
      float h = ov * tanhf(c);
      hbuf[t] = h;
      lout[((size_t)b * 50 + step) * 128 + t] = h;
    }
    __syncthreads();
  }
}

// ---------------------------------------------------------------------------
// Prediction head: p1 = lout . (pred_w^T tc) + tc . pred_b
// ---------------------------------------------------------------------------
__global__ __launch_bounds__(128) void k_pred(const float* __restrict__ lout,
    const float* __restrict__ pred_w, const float* __restrict__ pred_b,
    const float* __restrict__ tc, const float* __restrict__ result,
    float* __restrict__ out, float* __restrict__ fpbuf, float* __restrict__ mbuf) {
  int row = blockIdx.x; int k = threadIdx.x;
  __shared__ float tcs[101];
  __shared__ float r1[128], r2[128], r3[128];
  if (k < 101) tcs[k] = tc[(size_t)row * 101 + k];
  __syncthreads();
  float lk = lout[(size_t)row * 128 + k];
  float acc = 0.f;
  for (int c = 0; c < 101; c++) acc += tcs[c] * pred_w[c * 128 + k];
  float v = acc * lk;
  float pb = (k < 101) ? tcs[k] * pred_b[k] : 0.f;
  float nc = (k < 101) ? tcs[k] : 0.f;
  r1[k] = v; r2[k] = pb; r3[k] = nc;
  __syncthreads();
  for (int st = 64; st > 0; st >>= 1) {
    if (k < st) { r1[k] += r1[k + st]; r2[k] += r2[k + st]; r3[k] += r3[k + st]; }
    __syncthreads();
  }
  if (k == 0) {
    float ncon = r3[0];
    float m = (ncon > 0.f) ? 1.f : 0.f;
    float fp = (r1[0] + r2[0]) / fmaxf(ncon, 1.f);
    fpbuf[row] = fp; mbuf[row] = m;
    out[1 + row] = m / (1.f + expf(-fp));
    out[1 + NROW + row] = result[row] * m;
  }
}

// ---------------------------------------------------------------------------
// Loss reduction (single block, deterministic tree reduce)
// ---------------------------------------------------------------------------
__global__ __launch_bounds__(256) void k_loss(const float* __restrict__ fpbuf,
    const float* __restrict__ mbuf, const float* __restrict__ result,
    float* __restrict__ out) {
  __shared__ float sb[256], sm[256];
  int k = threadIdx.x;
  float ab = 0.f, am = 0.f;
  for (int r = k; r < NROW; r += 256) {
    float fp = fpbuf[r], m = mbuf[r], res = result[r];
    float bce = fmaxf(fp, 0.f) - fp * res + log1pf(expf(-fabsf(fp)));
    ab += bce * m; am += m;
  }
  sb[k] = ab; sm[k] = am;
  __syncthreads();
  for (int st = 128; st > 0; st >>= 1) {
    if (k < st) { sb[k] += sb[k + st]; sm[k] += sm[k + st]; }
    __syncthreads();
  }
  if (k == 0) out[0] = sb[0] / fmaxf(sm[0], 1.f);
}

// ---------------------------------------------------------------------------
extern "C" void kernel_launch(void* const* d_in, const int* in_sizes, int n_in,
                              void* d_out, int out_size, void* d_ws, size_t ws_size,
                              hipStream_t stream) {
  (void)in_sizes; (void)n_in; (void)out_size; (void)ws_size;
  const int*   ast      = (const int*)  d_in[2];
  const float* target_c = (const float*)d_in[3];
  const float* c_embed  = (const float*)d_in[4];
  const float* cur_res  = (const float*)d_in[5];
  const float* result   = (const float*)d_in[6];
  const float* emb      = (const float*)d_in[7];
  const float* Wc_w     = (const float*)d_in[8];
  const float* Wc_b     = (const float*)d_in[9];
  const float* gru_WxF  = (const float*)d_in[10];
  const float* gru_WhF  = (const float*)d_in[11];
  const float* gru_bxF  = (const float*)d_in[12];
  const float* gru_bhF  = (const float*)d_in[13];
  const float* gru_WxB  = (const float*)d_in[14];
  const float* gru_WhB  = (const float*)d_in[15];
  const float* gru_bxB  = (const float*)d_in[16];
  const float* gru_bhB  = (const float*)d_in[17];
  const float* lstm_Wx  = (const float*)d_in[18];
  const float* lstm_Wh  = (const float*)d_in[19];
  const float* lstm_bx  = (const float*)d_in[20];
  const float* lstm_bh  = (const float*)d_in[21];
  const float* pred_w   = (const float*)d_in[22];
  const float* pred_b   = (const float*)d_in[23];
  float* out = (float*)d_out;

  float* W = (float*)d_ws;
  float* Ep     = W;                 // 6,400,000 (VOCAB*128)
  float* xe_all = W;                 // alias: 25600*192 = 4,915,200 <= Ep size
  float* x      = W + 6400000;       // 3,276,800
  float* Wall   = W + 9676800;       // 24,576
  float* ball   = W + 9701376;       // 192
  float* code   = W + 9767104;       // 102,400
  float* lin    = W + 9869504;       // 267,200
  float* xeL    = W + 10136704;      // 819,200
  float* lout   = W + 10955904;      // 204,800
  float* fpbuf  = W + 11160704;      // 1,600
  float* mbuf   = W + 11162304;      // 1,600

  // 1. E' = emb @ Wc_w^T   (vocab-level projection)
  sgemm_nt<<<dim3(1, 782), 256, 0, stream>>>(emb, Wc_w, nullptr, Ep, VOCAB, 128, 128);
  // 2. weight prep
  k_prep<<<256, 256, 0, stream>>>(gru_WxF, gru_WxB, gru_bxF, gru_bxB, Wall, ball);
  // 3. tree gather/sum/max -> x (25600 x 128)
  k_tree<<<NTREE / 2, 256, 0, stream>>>(ast, Ep, Wc_b, x);
  // 4. xe_all = x @ Wall^T + ball  (25600 x 192)  [aliases Ep region]
  sgemm_nt<<<dim3(2, 400), 256, 0, stream>>>(x, Wall, ball, xe_all, NTREE, 192, 128);
  // 5. GRU recurrence + time max -> code (1600 x 64)
  k_gru<<<NROW * 2, 128, 0, stream>>>(xe_all, gru_WhF, gru_WhB, gru_bhF, gru_bhB, code);
  // 6. lin build (1600 x 167)
  k_lin<<<(NROW * LIN_D + 255) / 256, 256, 0, stream>>>(c_embed, code, cur_res, lin);
  // 7. xeL = lin @ lstm_Wx^T + lstm_bx (1600 x 512)
  sgemm_nt<<<dim3(4, 25), 256, 0, stream>>>(lin, lstm_Wx, lstm_bx, xeL, NROW, 512, LIN_D);
  // 8. LSTM recurrence -> lout (1600 x 128)  [split-row, 1024 thr, no spill]
  k_lstm<<<BS, 1024, 0, stream>>>(xeL, lstm_Wh, lstm_bh, lout);
  // 9. prediction head -> out[1..], fpbuf, mbuf
  k_pred<<<NROW, 128, 0, stream>>>(lout, pred_w, pred_b, target_c, result,
                                   out, fpbuf, mbuf);
  // 10. loss -> out[0]
  k_loss<<<1, 256, 0, stream>>>(fpbuf, mbuf, result, out);
}

// Round 7
// 246.929 us; speedup vs baseline: 1.0410x; 1.0410x over previous
//
#include <hip/hip_runtime.h>
#include <hip/hip_bf16.h>
#include <math.h>

// Problem constants
#define BS 32
#define SEQ 50
#define ML 16
#define NN 15
#define NTREE (BS*SEQ*ML)     // 25600
#define NROW (BS*SEQ)         // 1600
#define VOCAB 50000
#define EMB 128
#define ENC 128
#define GH 32
#define NC 100
#define LH 128
#define LIN_D 167             // 101 + 64 + 2

typedef float f32x4 __attribute__((ext_vector_type(4)));

// ---------------------------------------------------------------------------
// fp32 GEMM: C[M][N] = A[M][K] @ B[N][K]^T (+ bias[N])
// BM=64 x BN=128 tile, BK=32, 256 threads, 4x8 per thread.
// ---------------------------------------------------------------------------
__global__ __launch_bounds__(256) void sgemm_nt(const float* __restrict__ A,
    const float* __restrict__ B, const float* __restrict__ bias,
    float* __restrict__ C, int M, int N, int K) {
  __shared__ float As[32][68];    // [k][m]
  __shared__ float Bs[32][132];   // [k][n]
  const int bm = blockIdx.y * 64, bn = blockIdx.x * 128;
  const int tid = threadIdx.x;
  const int tm = (tid >> 4) << 2;   // 0..60
  const int tn = (tid & 15) << 3;   // 0..120
  const int srow = tid >> 3;        // 0..31
  const int q4 = (tid & 7) << 2;    // 0,4,..,28
  const bool vec_ok = ((K & 3) == 0);

  float acc[4][8];
  #pragma unroll
  for (int i = 0; i < 4; i++)
    #pragma unroll
    for (int j = 0; j < 8; j++) acc[i][j] = 0.f;

  for (int k0 = 0; k0 < K; k0 += 32) {
    if (vec_ok && (k0 + 32 <= K)) {
      #pragma unroll
      for (int h = 0; h < 2; h++) {
        int gm = bm + srow + h * 32;
        int rm = (gm < M) ? gm : (M - 1);
        float4 av = *(const float4*)&A[(size_t)rm * K + k0 + q4];
        As[q4 + 0][srow + h * 32] = av.x;
        As[q4 + 1][srow + h * 32] = av.y;
        As[q4 + 2][srow + h * 32] = av.z;
        As[q4 + 3][srow + h * 32] = av.w;
      }
      #pragma unroll
      for (int h = 0; h < 4; h++) {
        int gn = bn + srow + h * 32;
        float4 bv = make_float4(0.f, 0.f, 0.f, 0.f);
        if (gn < N) bv = *(const float4*)&B[(size_t)gn * K + k0 + q4];
        Bs[q4 + 0][srow + h * 32] = bv.x;
        Bs[q4 + 1][srow + h * 32] = bv.y;
        Bs[q4 + 2][srow + h * 32] = bv.z;
        Bs[q4 + 3][srow + h * 32] = bv.w;
      }
    } else {
      #pragma unroll
      for (int h = 0; h < 2; h++) {
        int gm = bm + srow + h * 32;
        int rm = (gm < M) ? gm : (M - 1);
        #pragma unroll
        for (int j = 0; j < 4; j++) {
          int gk = k0 + q4 + j;
          As[q4 + j][srow + h * 32] = (gk < K) ? A[(size_t)rm * K + gk] : 0.f;
        }
      }
      #pragma unroll
      for (int h = 0; h < 4; h++) {
        int gn = bn + srow + h * 32;
        #pragma unroll
        for (int j = 0; j < 4; j++) {
          int gk = k0 + q4 + j;
          Bs[q4 + j][srow + h * 32] =
              (gn < N && gk < K) ? B[(size_t)gn * K + gk] : 0.f;
        }
      }
    }
    __syncthreads();
    #pragma unroll
    for (int kk = 0; kk < 32; kk++) {
      float4 a4 = *(const float4*)&As[kk][tm];
      float4 b0 = *(const float4*)&Bs[kk][tn];
      float4 b1 = *(const float4*)&Bs[kk][tn + 4];
      float a[4] = {a4.x, a4.y, a4.z, a4.w};
      float b[8] = {b0.x, b0.y, b0.z, b0.w, b1.x, b1.y, b1.z, b1.w};
      #pragma unroll
      for (int i = 0; i < 4; i++)
        #pragma unroll
        for (int j = 0; j < 8; j++) acc[i][j] += a[i] * b[j];
    }
    __syncthreads();
  }

  float bb[8];
  #pragma unroll
  for (int j = 0; j < 8; j++) {
    int gn = bn + tn + j;
    bb[j] = (bias && gn < N) ? bias[gn] : 0.f;
  }
  if (bn + tn < N) {
    #pragma unroll
    for (int i = 0; i < 4; i++) {
      int gm = bm + tm + i;
      if (gm >= M) continue;
      float4 v0 = make_float4(acc[i][0] + bb[0], acc[i][1] + bb[1],
                              acc[i][2] + bb[2], acc[i][3] + bb[3]);
      float4 v1 = make_float4(acc[i][4] + bb[4], acc[i][5] + bb[5],
                              acc[i][6] + bb[6], acc[i][7] + bb[7]);
      *(float4*)&C[(size_t)gm * N + bn + tn] = v0;
      *(float4*)&C[(size_t)gm * N + bn + tn + 4] = v1;
    }
  }
}

// ---------------------------------------------------------------------------
// Prep: Wall = [WxF; WxB] (192x128), ball = [bxF; bxB]
// ---------------------------------------------------------------------------
__global__ __launch_bounds__(256) void k_prep(const float* __restrict__ WxF,
    const float* __restrict__ WxB, const float* __restrict__ bxF,
    const float* __restrict__ bxB,
    float* __restrict__ Wall, float* __restrict__ ball) {
  int i = blockIdx.x * 256 + threadIdx.x;
  if (i < 96 * 128) Wall[i] = WxF[i];
  else if (i < 192 * 128) Wall[i] = WxB[i - 96 * 128];
  if (i < 96) ball[i] = bxF[i];
  else if (i < 192) ball[i] = bxB[i - 96];
}

// ---------------------------------------------------------------------------
// Tree: gather 15 rows of E', bottom-up subtree sums, node max. 2 trees/block.
// ---------------------------------------------------------------------------
__global__ __launch_bounds__(256) void k_tree(const int* __restrict__ ast,
    const float* __restrict__ Ep, const float* __restrict__ Wc_b,
    float* __restrict__ x) {
  int lt = threadIdx.x >> 7;      // 0/1
  int d  = threadIdx.x & 127;
  int tree = blockIdx.x * 2 + lt;
  __shared__ int toks[2][15];
  if (d < 15) toks[lt][d] = ast[(size_t)tree * 15 + d];
  __syncthreads();
  float e[15];
  #pragma unroll
  for (int n = 0; n < 15; n++) e[n] = Ep[(size_t)toks[lt][n] * 128 + d];
  float b = Wc_b[d];
  float s3 = e[3] + e[7] + e[8],  s4 = e[4] + e[9] + e[10];
  float s5 = e[5] + e[11] + e[12], s6 = e[6] + e[13] + e[14];
  float s1 = e[1] + s3 + s4, s2 = e[2] + s5 + s6;
  float s0 = e[0] + s1 + s2;
  float ml = fmaxf(fmaxf(fmaxf(e[7], e[8]), fmaxf(e[9], e[10])),
                   fmaxf(fmaxf(e[11], e[12]), fmaxf(e[13], e[14]))) + b;
  float mm = fmaxf(fmaxf(s3, s4), fmaxf(s5, s6)) + 3.f * b;
  float mt = fmaxf(s1, s2) + 7.f * b;
  float m = fmaxf(fmaxf(ml, mm), fmaxf(mt, s0 + 15.f * b));
  x[(size_t)tree * 128 + d] = m;
}

// ---------------------------------------------------------------------------
// GRU recurrence, one block per (sequence, direction). Hidden=32, gates=96.
// ---------------------------------------------------------------------------
__global__ __launch_bounds__(128) void k_gru(const float* __restrict__ xe_all,
    const float* __restrict__ WhF, const float* __restrict__ WhB,
    const float* __restrict__ bhF, const float* __restrict__ bhB,
    float* __restrict__ code) {
  int bsq = blockIdx.x >> 1, dir = blockIdx.x & 1;
  int g = threadIdx.x;
  __shared__ float whs[96 * 32];
  __shared__ float h_lds[32];
  __shared__ float rz[64];
  __shared__ float nn[32];
  const float* Wh = dir ? WhB : WhF;
  const float* bh = dir ? bhB : bhF;
  for (int i = g; i < 96 * 32; i += 128) whs[i] = Wh[i];
  if (g < 32) h_lds[g] = 0.f;
  __syncthreads();
  float w[32]; float bhv = 0.f, mxv = -1e30f;
  if (g < 96) {
    #pragma unroll
    for (int j = 0; j < 32; j++) w[j] = whs[g * 32 + j];
    bhv = bh[g];
  }
  for (int s = 0; s < 16; s++) {
    int t = dir ? (15 - s) : s;
    const float* xe = xe_all + ((size_t)(bsq * 16 + t)) * 192 + dir * 96;
    float gh = bhv, xv = 0.f;
    if (g < 96) {
      xv = xe[g];
      #pragma unroll
      for (int j = 0; j < 32; j++) gh += w[j] * h_lds[j];
    }
    if (g < 64) rz[g] = 1.f / (1.f + expf(-(xv + gh)));
    __syncthreads();
    if (g >= 64 && g < 96) nn[g - 64] = tanhf(xv + rz[g - 64] * gh);
    __syncthreads();
    if (g < 32) {
      float z = rz[g + 32];
      float hn = (1.f - z) * nn[g] + z * h_lds[g];
      mxv = fmaxf(mxv, hn);
      h_lds[g] = hn;
    }
    __syncthreads();
  }
  if (g < 32) code[(size_t)bsq * 64 + dir * 32 + g] = mxv;
}

// ---------------------------------------------------------------------------
// Build lin = [c_embed(101) | code(64) | cur_result(2)]
// ---------------------------------------------------------------------------
__global__ __launch_bounds__(256) void k_lin(const float* __restrict__ c_embed,
    const float* __restrict__ code, const float* __restrict__ cur,
    float* __restrict__ lin) {
  int i = blockIdx.x * 256 + threadIdx.x;
  if (i >= NROW * LIN_D) return;
  int row = i / LIN_D, j = i - row * LIN_D;
  float v;
  if (j < 101) v = c_embed[row * 101 + j];
  else if (j < 165) v = code[row * 64 + (j - 101)];
  else v = cur[row * 2 + (j - 165)];
  lin[i] = v;
}

// ---------------------------------------------------------------------------
// LSTM v6: 32 blocks x 512 threads. Thread t owns gate row t (32 float4 =
// 128 VGPR, asm-pinned loads). amdgpu_waves_per_eu(2,2) pins the register
// allocator's occupancy TARGET to 2 waves/EU (256-VGPR budget) so the
// pressure-reduction stage never spills the weights (launch_bounds' 2nd arg
// only sets the MINIMUM; the default max=8 target caused 3 rounds of spill).
// h broadcast: 2 ds_read_b32 + 128 v_readlane per thread per step.
// ---------------------------------------------------------------------------
#define RL(v, l) __int_as_float(__builtin_amdgcn_readlane(__float_as_int(v), (l)))

__global__ __attribute__((amdgpu_flat_work_group_size(512, 512),
                          amdgpu_waves_per_eu(2, 2)))
void k_lstm(const float* __restrict__ xeL,
    const float* __restrict__ Wh, const float* __restrict__ bh,
    float* __restrict__ lout) {
  int b = blockIdx.x; int t = threadIdx.x;
  int lane = t & 63;
  __shared__ float hbuf[128];
  __shared__ float ga[512];
  // --- force-load this thread's weight row into 32 VGPR quads ---
  f32x4 w[32];
  const float* base = Wh + (size_t)t * 128;
  #pragma unroll
  for (int j = 0; j < 8; j++) {
    asm volatile("global_load_dwordx4 %0, %1, off offset:%2"
                 : "=v"(w[4*j+0]) : "v"(base), "i"(j*64+0));
    asm volatile("global_load_dwordx4 %0, %1, off offset:%2"
                 : "=v"(w[4*j+1]) : "v"(base), "i"(j*64+16));
    asm volatile("global_load_dwordx4 %0, %1, off offset:%2"
                 : "=v"(w[4*j+2]) : "v"(base), "i"(j*64+32));
    asm volatile("global_load_dwordx4 %0, %1, off offset:%2"
                 : "=v"(w[4*j+3]) : "v"(base), "i"(j*64+48));
  }
  asm volatile("s_waitcnt vmcnt(0)" ::: "memory");
  __builtin_amdgcn_sched_barrier(0);

  float bhv = bh[t];
  float c = 0.f;
  if (t < 128) hbuf[t] = 0.f;
  const float* xrow = xeL + (size_t)b * 50 * 512;
  float xe = xrow[t];                 // step-0 prefetch
  __syncthreads();
  for (int step = 0; step < 50; step++) {
    float h0 = hbuf[lane];
    float h1 = hbuf[64 + lane];
    float acc_a = xe + bhv, acc_b = 0.f;
    if (step < 49) xe = xrow[(size_t)(step + 1) * 512 + t];
    #pragma unroll
    for (int i = 0; i < 16; i++) {
      f32x4 a = w[i];
      acc_a += RL(h0, 4*i+0) * a.x;
      acc_b += RL(h0, 4*i+1) * a.y;
      acc_a += RL(h0, 4*i+2) * a.z;
      acc_b += RL(h0, 4*i+3) * a.w;
    }
    #pragma unroll
    for (int i = 0; i < 16; i++) {
      f32x4 a = w[16 + i];
      acc_a += RL(h1, 4*i+0) * a.x;
      acc_b += RL(h1, 4*i+1) * a.y;
      acc_a += RL(h1, 4*i+2) * a.z;
      acc_b += RL(h1, 4*i+3) * a.w;
    }
    ga[t] = acc_a + acc_b;
    __syncthreads();
    if (t < 128) {
      float iv = 1.f / (1.f + expf(-ga[t]));
      float fv = 1.f / (1.f + expf(-ga[t + 128]));
      float gv = tanhf(ga[t + 256]);
      float ov = 1.f / (1.f + expf(-ga[t + 384]));
      c = fv * c + iv * gv;
      float h = ov * tanhf(c);
      hbuf[t] = h;
      lout[((size_t)b * 50 + step) * 128 + t] = h;
    }
    __syncthreads();
  }
}

// ---------------------------------------------------------------------------
// Prediction head: p1 = lout . (pred_w^T tc) + tc . pred_b
// ---------------------------------------------------------------------------
__global__ __launch_bounds__(128) void k_pred(const float* __restrict__ lout,
    const float* __restrict__ pred_w, const float* __restrict__ pred_b,
    const float* __restrict__ tc, const float* __restrict__ result,
    float* __restrict__ out, float* __restrict__ fpbuf, float* __restrict__ mbuf) {
  int row = blockIdx.x; int k = threadIdx.x;
  __shared__ float tcs[101];
  __shared__ float r1[128], r2[128], r3[128];
  if (k < 101) tcs[k] = tc[(size_t)row * 101 + k];
  __syncthreads();
  float lk = lout[(size_t)row * 128 + k];
  float acc = 0.f;
  for (int c = 0; c < 101; c++) acc += tcs[c] * pred_w[c * 128 + k];
  float v = acc * lk;
  float pb = (k < 101) ? tcs[k] * pred_b[k] : 0.f;
  float nc = (k < 101) ? tcs[k] : 0.f;
  r1[k] = v; r2[k] = pb; r3[k] = nc;
  __syncthreads();
  for (int st = 64; st > 0; st >>= 1) {
    if (k < st) { r1[k] += r1[k + st]; r2[k] += r2[k + st]; r3[k] += r3[k + st]; }
    __syncthreads();
  }
  if (k == 0) {
    float ncon = r3[0];
    float m = (ncon > 0.f) ? 1.f : 0.f;
    float fp = (r1[0] + r2[0]) / fmaxf(ncon, 1.f);
    fpbuf[row] = fp; mbuf[row] = m;
    out[1 + row] = m / (1.f + expf(-fp));
    out[1 + NROW + row] = result[row] * m;
  }
}

// ---------------------------------------------------------------------------
// Loss reduction (single block, deterministic tree reduce)
// ---------------------------------------------------------------------------
__global__ __launch_bounds__(256) void k_loss(const float* __restrict__ fpbuf,
    const float* __restrict__ mbuf, const float* __restrict__ result,
    float* __restrict__ out) {
  __shared__ float sb[256], sm[256];
  int k = threadIdx.x;
  float ab = 0.f, am = 0.f;
  for (int r = k; r < NROW; r += 256) {
    float fp = fpbuf[r], m = mbuf[r], res = result[r];
    float bce = fmaxf(fp, 0.f) - fp * res + log1pf(expf(-fabsf(fp)));
    ab += bce * m; am += m;
  }
  sb[k] = ab; sm[k] = am;
  __syncthreads();
  for (int st = 128; st > 0; st >>= 1) {
    if (k < st) { sb[k] += sb[k + st]; sm[k] += sm[k + st]; }
    __syncthreads();
  }
  if (k == 0) out[0] = sb[0] / fmaxf(sm[0], 1.f);
}

// ---------------------------------------------------------------------------
extern "C" void kernel_launch(void* const* d_in, const int* in_sizes, int n_in,
                              void* d_out, int out_size, void* d_ws, size_t ws_size,
                              hipStream_t stream) {
  (void)in_sizes; (void)n_in; (void)out_size; (void)ws_size;
  const int*   ast      = (const int*)  d_in[2];
  const float* target_c = (const float*)d_in[3];
  const float* c_embed  = (const float*)d_in[4];
  const float* cur_res  = (const float*)d_in[5];
  const float* result   = (const float*)d_in[6];
  const float* emb      = (const float*)d_in[7];
  const float* Wc_w     = (const float*)d_in[8];
  const float* Wc_b     = (const float*)d_in[9];
  const float* gru_WxF  = (const float*)d_in[10];
  const float* gru_WhF  = (const float*)d_in[11];
  const float* gru_bxF  = (const float*)d_in[12];
  const float* gru_bhF  = (const float*)d_in[13];
  const float* gru_WxB  = (const float*)d_in[14];
  const float* gru_WhB  = (const float*)d_in[15];
  const float* gru_bxB  = (const float*)d_in[16];
  const float* gru_bhB  = (const float*)d_in[17];
  const float* lstm_Wx  = (const float*)d_in[18];
  const float* lstm_Wh  = (const float*)d_in[19];
  const float* lstm_bx  = (const float*)d_in[20];
  const float* lstm_bh  = (const float*)d_in[21];
  const float* pred_w   = (const float*)d_in[22];
  const float* pred_b   = (const float*)d_in[23];
  float* out = (float*)d_out;

  float* W = (float*)d_ws;
  float* Ep     = W;                 // 6,400,000 (VOCAB*128)
  float* xe_all = W;                 // alias: 25600*192 = 4,915,200 <= Ep size
  float* x      = W + 6400000;       // 3,276,800
  float* Wall   = W + 9676800;       // 24,576
  float* ball   = W + 9701376;       // 192
  float* code   = W + 9767104;       // 102,400
  float* lin    = W + 9869504;       // 267,200
  float* xeL    = W + 10136704;      // 819,200
  float* lout   = W + 10955904;      // 204,800
  float* fpbuf  = W + 11160704;      // 1,600
  float* mbuf   = W + 11162304;      // 1,600

  // 1. E' = emb @ Wc_w^T   (vocab-level projection)
  sgemm_nt<<<dim3(1, 782), 256, 0, stream>>>(emb, Wc_w, nullptr, Ep, VOCAB, 128, 128);
  // 2. weight prep
  k_prep<<<256, 256, 0, stream>>>(gru_WxF, gru_WxB, gru_bxF, gru_bxB, Wall, ball);
  // 3. tree gather/sum/max -> x (25600 x 128)
  k_tree<<<NTREE / 2, 256, 0, stream>>>(ast, Ep, Wc_b, x);
  // 4. xe_all = x @ Wall^T + ball  (25600 x 192)  [aliases Ep region]
  sgemm_nt<<<dim3(2, 400), 256, 0, stream>>>(x, Wall, ball, xe_all, NTREE, 192, 128);
  // 5. GRU recurrence + time max -> code (1600 x 64)
  k_gru<<<NROW * 2, 128, 0, stream>>>(xe_all, gru_WhF, gru_WhB, gru_bhF, gru_bhB, code);
  // 6. lin build (1600 x 167)
  k_lin<<<(NROW * LIN_D + 255) / 256, 256, 0, stream>>>(c_embed, code, cur_res, lin);
  // 7. xeL = lin @ lstm_Wx^T + lstm_bx (1600 x 512)
  sgemm_nt<<<dim3(4, 25), 256, 0, stream>>>(lin, lstm_Wx, lstm_bx, xeL, NROW, 512, LIN_D);
  // 8. LSTM recurrence -> lout (1600 x 128)  [waves_per_eu(2,2): no spill]
  k_lstm<<<BS, 512, 0, stream>>>(xeL, lstm_Wh, lstm_bh, lout);
  // 9. prediction head -> out[1..], fpbuf, mbuf
  k_pred<<<NROW, 128, 0, stream>>>(lout, pred_w, pred_b, target_c, result,
                                   out, fpbuf, mbuf);
  // 10. loss -> out[0]
  k_loss<<<1, 256, 0, stream>>>(fpbuf, mbuf, result, out);
}

// Round 8
// 234.162 us; speedup vs baseline: 1.0978x; 1.0545x over previous
//
#include <hip/hip_runtime.h>
#include <hip/hip_bf16.h>
#include <math.h>

// Problem constants
#define BS 32
#define SEQ 50
#define ML 16
#define NN 15
#define NTREE (BS*SEQ*ML)     // 25600
#define NROW (BS*SEQ)         // 1600
#define VOCAB 50000
#define EMB 128
#define ENC 128
#define GH 32
#define NC 100
#define LH 128
#define LIN_D 167             // 101 + 64 + 2
#define LIN_P 192             // padded K for the xeL GEMM (vector path)

typedef float f32x4 __attribute__((ext_vector_type(4)));

// ---------------------------------------------------------------------------
// fp32 GEMM: C[M][N] = A[M][K] @ B[N][K]^T (+ bias[N])
// BM=64 x BN=128 tile, BK=32, 256 threads, 4x8 per thread.
// ---------------------------------------------------------------------------
__global__ __launch_bounds__(256) void sgemm_nt(const float* __restrict__ A,
    const float* __restrict__ B, const float* __restrict__ bias,
    float* __restrict__ C, int M, int N, int K) {
  __shared__ float As[32][68];    // [k][m]
  __shared__ float Bs[32][132];   // [k][n]
  const int bm = blockIdx.y * 64, bn = blockIdx.x * 128;
  const int tid = threadIdx.x;
  const int tm = (tid >> 4) << 2;   // 0..60
  const int tn = (tid & 15) << 3;   // 0..120
  const int srow = tid >> 3;        // 0..31
  const int q4 = (tid & 7) << 2;    // 0,4,..,28
  const bool vec_ok = ((K & 3) == 0);

  float acc[4][8];
  #pragma unroll
  for (int i = 0; i < 4; i++)
    #pragma unroll
    for (int j = 0; j < 8; j++) acc[i][j] = 0.f;

  for (int k0 = 0; k0 < K; k0 += 32) {
    if (vec_ok && (k0 + 32 <= K)) {
      #pragma unroll
      for (int h = 0; h < 2; h++) {
        int gm = bm + srow + h * 32;
        int rm = (gm < M) ? gm : (M - 1);
        float4 av = *(const float4*)&A[(size_t)rm * K + k0 + q4];
        As[q4 + 0][srow + h * 32] = av.x;
        As[q4 + 1][srow + h * 32] = av.y;
        As[q4 + 2][srow + h * 32] = av.z;
        As[q4 + 3][srow + h * 32] = av.w;
      }
      #pragma unroll
      for (int h = 0; h < 4; h++) {
        int gn = bn + srow + h * 32;
        float4 bv = make_float4(0.f, 0.f, 0.f, 0.f);
        if (gn < N) bv = *(const float4*)&B[(size_t)gn * K + k0 + q4];
        Bs[q4 + 0][srow + h * 32] = bv.x;
        Bs[q4 + 1][srow + h * 32] = bv.y;
        Bs[q4 + 2][srow + h * 32] = bv.z;
        Bs[q4 + 3][srow + h * 32] = bv.w;
      }
    } else {
      #pragma unroll
      for (int h = 0; h < 2; h++) {
        int gm = bm + srow + h * 32;
        int rm = (gm < M) ? gm : (M - 1);
        #pragma unroll
        for (int j = 0; j < 4; j++) {
          int gk = k0 + q4 + j;
          As[q4 + j][srow + h * 32] = (gk < K) ? A[(size_t)rm * K + gk] : 0.f;
        }
      }
      #pragma unroll
      for (int h = 0; h < 4; h++) {
        int gn = bn + srow + h * 32;
        #pragma unroll
        for (int j = 0; j < 4; j++) {
          int gk = k0 + q4 + j;
          Bs[q4 + j][srow + h * 32] =
              (gn < N && gk < K) ? B[(size_t)gn * K + gk] : 0.f;
        }
      }
    }
    __syncthreads();
    #pragma unroll
    for (int kk = 0; kk < 32; kk++) {
      float4 a4 = *(const float4*)&As[kk][tm];
      float4 b0 = *(const float4*)&Bs[kk][tn];
      float4 b1 = *(const float4*)&Bs[kk][tn + 4];
      float a[4] = {a4.x, a4.y, a4.z, a4.w};
      float b[8] = {b0.x, b0.y, b0.z, b0.w, b1.x, b1.y, b1.z, b1.w};
      #pragma unroll
      for (int i = 0; i < 4; i++)
        #pragma unroll
        for (int j = 0; j < 8; j++) acc[i][j] += a[i] * b[j];
    }
    __syncthreads();
  }

  float bb[8];
  #pragma unroll
  for (int j = 0; j < 8; j++) {
    int gn = bn + tn + j;
    bb[j] = (bias && gn < N) ? bias[gn] : 0.f;
  }
  if (bn + tn < N) {
    #pragma unroll
    for (int i = 0; i < 4; i++) {
      int gm = bm + tm + i;
      if (gm >= M) continue;
      float4 v0 = make_float4(acc[i][0] + bb[0], acc[i][1] + bb[1],
                              acc[i][2] + bb[2], acc[i][3] + bb[3]);
      float4 v1 = make_float4(acc[i][4] + bb[4], acc[i][5] + bb[5],
                              acc[i][6] + bb[6], acc[i][7] + bb[7]);
      *(float4*)&C[(size_t)gm * N + bn + tn] = v0;
      *(float4*)&C[(size_t)gm * N + bn + tn + 4] = v1;
    }
  }
}

// ---------------------------------------------------------------------------
// Prep: Wall = [WxF; WxB] (192x128), ball = [bxF; bxB],
//       Wxp = lstm_Wx zero-padded K 167 -> 192 (512 x 192)
// ---------------------------------------------------------------------------
__global__ __launch_bounds__(256) void k_prep(const float* __restrict__ WxF,
    const float* __restrict__ WxB, const float* __restrict__ bxF,
    const float* __restrict__ bxB, const float* __restrict__ lstm_Wx,
    float* __restrict__ Wall, float* __restrict__ ball,
    float* __restrict__ Wxp) {
  int i = blockIdx.x * 256 + threadIdx.x;
  if (i < 96 * 128) Wall[i] = WxF[i];
  else if (i < 192 * 128) Wall[i] = WxB[i - 96 * 128];
  if (i < 96) ball[i] = bxF[i];
  else if (i < 192) ball[i] = bxB[i - 96];
  if (i < 512 * LIN_P) {
    int n = i / LIN_P, k = i - n * LIN_P;
    Wxp[i] = (k < LIN_D) ? lstm_Wx[n * LIN_D + k] : 0.f;
  }
}

// ---------------------------------------------------------------------------
// Tree: gather 15 rows of E', bottom-up subtree sums, node max. 2 trees/block.
// ---------------------------------------------------------------------------
__global__ __launch_bounds__(256) void k_tree(const int* __restrict__ ast,
    const float* __restrict__ Ep, const float* __restrict__ Wc_b,
    float* __restrict__ x) {
  int lt = threadIdx.x >> 7;      // 0/1
  int d  = threadIdx.x & 127;
  int tree = blockIdx.x * 2 + lt;
  __shared__ int toks[2][15];
  if (d < 15) toks[lt][d] = ast[(size_t)tree * 15 + d];
  __syncthreads();
  float e[15];
  #pragma unroll
  for (int n = 0; n < 15; n++) e[n] = Ep[(size_t)toks[lt][n] * 128 + d];
  float b = Wc_b[d];
  float s3 = e[3] + e[7] + e[8],  s4 = e[4] + e[9] + e[10];
  float s5 = e[5] + e[11] + e[12], s6 = e[6] + e[13] + e[14];
  float s1 = e[1] + s3 + s4, s2 = e[2] + s5 + s6;
  float s0 = e[0] + s1 + s2;
  float ml = fmaxf(fmaxf(fmaxf(e[7], e[8]), fmaxf(e[9], e[10])),
                   fmaxf(fmaxf(e[11], e[12]), fmaxf(e[13], e[14]))) + b;
  float mm = fmaxf(fmaxf(s3, s4), fmaxf(s5, s6)) + 3.f * b;
  float mt = fmaxf(s1, s2) + 7.f * b;
  float m = fmaxf(fmaxf(ml, mm), fmaxf(mt, s0 + 15.f * b));
  x[(size_t)tree * 128 + d] = m;
}

// ---------------------------------------------------------------------------
// GRU recurrence, one block per (sequence, direction). Hidden=32, gates=96.
// ---------------------------------------------------------------------------
__global__ __launch_bounds__(128) void k_gru(const float* __restrict__ xe_all,
    const float* __restrict__ WhF, const float* __restrict__ WhB,
    const float* __restrict__ bhF, const float* __restrict__ bhB,
    float* __restrict__ code) {
  int bsq = blockIdx.x >> 1, dir = blockIdx.x & 1;
  int g = threadIdx.x;
  __shared__ float whs[96 * 32];
  __shared__ float h_lds[32];
  __shared__ float rz[64];
  __shared__ float nn[32];
  const float* Wh = dir ? WhB : WhF;
  const float* bh = dir ? bhB : bhF;
  for (int i = g; i < 96 * 32; i += 128) whs[i] = Wh[i];
  if (g < 32) h_lds[g] = 0.f;
  __syncthreads();
  float w[32]; float bhv = 0.f, mxv = -1e30f;
  if (g < 96) {
    #pragma unroll
    for (int j = 0; j < 32; j++) w[j] = whs[g * 32 + j];
    bhv = bh[g];
  }
  for (int s = 0; s < 16; s++) {
    int t = dir ? (15 - s) : s;
    const float* xe = xe_all + ((size_t)(bsq * 16 + t)) * 192 + dir * 96;
    float gh = bhv, xv = 0.f;
    if (g < 96) {
      xv = xe[g];
      #pragma unroll
      for (int j = 0; j < 32; j++) gh += w[j] * h_lds[j];
    }
    if (g < 64) rz[g] = 1.f / (1.f + expf(-(xv + gh)));
    __syncthreads();
    if (g >= 64 && g < 96) nn[g - 64] = tanhf(xv + rz[g - 64] * gh);
    __syncthreads();
    if (g < 32) {
      float z = rz[g + 32];
      float hn = (1.f - z) * nn[g] + z * h_lds[g];
      mxv = fmaxf(mxv, hn);
      h_lds[g] = hn;
    }
    __syncthreads();
  }
  if (g < 32) code[(size_t)bsq * 64 + dir * 32 + g] = mxv;
}

// ---------------------------------------------------------------------------
// Build lin = [c_embed(101) | code(64) | cur_result(2) | 0-pad to 192]
// ---------------------------------------------------------------------------
__global__ __launch_bounds__(256) void k_lin(const float* __restrict__ c_embed,
    const float* __restrict__ code, const float* __restrict__ cur,
    float* __restrict__ lin) {
  int i = blockIdx.x * 256 + threadIdx.x;
  if (i >= NROW * LIN_P) return;
  int row = i / LIN_P, j = i - row * LIN_P;
  float v;
  if (j < 101) v = c_embed[row * 101 + j];
  else if (j < 165) v = code[row * 64 + (j - 101)];
  else if (j < 167) v = cur[row * 2 + (j - 165)];
  else v = 0.f;
  lin[i] = v;
}

// ---------------------------------------------------------------------------
// LSTM v7: 32 blocks x 512 threads. Thread t owns gate row t held in 32
// INDIVIDUALLY NAMED f32x4 (no array -> nothing for SROA to leave in
// scratch; R2-R6 all spilled because the aggregate alloca survived).
// Loads are asm-pinned global_load_dwordx4 with literal offsets.
// waves_per_eu(2,2) gives a 256-VGPR budget for the ~160 live regs.
// ---------------------------------------------------------------------------
#define RL(v, l) __int_as_float(__builtin_amdgcn_readlane(__float_as_int(v), (l)))

#define LOADW(W, OFF) \
  asm volatile("global_load_dwordx4 %0, %1, off offset:" #OFF \
               : "=v"(W) : "v"(base));

#define MAC4(W, H, L0, L1, L2, L3) \
  acc_a += RL(H, L0) * W.x; acc_b += RL(H, L1) * W.y; \
  acc_a += RL(H, L2) * W.z; acc_b += RL(H, L3) * W.w;

__global__ __attribute__((amdgpu_flat_work_group_size(512, 512),
                          amdgpu_waves_per_eu(2, 2)))
void k_lstm(const float* __restrict__ xeL,
    const float* __restrict__ Wh, const float* __restrict__ bh,
    float* __restrict__ lout) {
  int b = blockIdx.x; int t = threadIdx.x;
  int lane = t & 63;
  __shared__ float hbuf[128];
  __shared__ float ga[512];
  f32x4 w00, w01, w02, w03, w04, w05, w06, w07;
  f32x4 w08, w09, w10, w11, w12, w13, w14, w15;
  f32x4 w16, w17, w18, w19, w20, w21, w22, w23;
  f32x4 w24, w25, w26, w27, w28, w29, w30, w31;
  const float* base = Wh + (size_t)t * 128;
  LOADW(w00,   0) LOADW(w01,  16) LOADW(w02,  32) LOADW(w03,  48)
  LOADW(w04,  64) LOADW(w05,  80) LOADW(w06,  96) LOADW(w07, 112)
  LOADW(w08, 128) LOADW(w09, 144) LOADW(w10, 160) LOADW(w11, 176)
  LOADW(w12, 192) LOADW(w13, 208) LOADW(w14, 224) LOADW(w15, 240)
  LOADW(w16, 256) LOADW(w17, 272) LOADW(w18, 288) LOADW(w19, 304)
  LOADW(w20, 320) LOADW(w21, 336) LOADW(w22, 352) LOADW(w23, 368)
  LOADW(w24, 384) LOADW(w25, 400) LOADW(w26, 416) LOADW(w27, 432)
  LOADW(w28, 448) LOADW(w29, 464) LOADW(w30, 480) LOADW(w31, 496)
  asm volatile("s_waitcnt vmcnt(0)" ::: "memory");
  __builtin_amdgcn_sched_barrier(0);

  float bhv = bh[t];
  float c = 0.f;
  if (t < 128) hbuf[t] = 0.f;
  const float* xrow = xeL + (size_t)b * 50 * 512;
  float xe = xrow[t];                 // step-0 prefetch
  __syncthreads();
  for (int step = 0; step < 50; step++) {
    float h0 = hbuf[lane];
    float h1 = hbuf[64 + lane];
    float acc_a = xe + bhv, acc_b = 0.f;
    if (step < 49) xe = xrow[(size_t)(step + 1) * 512 + t];
    MAC4(w00, h0,  0,  1,  2,  3)  MAC4(w01, h0,  4,  5,  6,  7)
    MAC4(w02, h0,  8,  9, 10, 11)  MAC4(w03, h0, 12, 13, 14, 15)
    MAC4(w04, h0, 16, 17, 18, 19)  MAC4(w05, h0, 20, 21, 22, 23)
    MAC4(w06, h0, 24, 25, 26, 27)  MAC4(w07, h0, 28, 29, 30, 31)
    MAC4(w08, h0, 32, 33, 34, 35)  MAC4(w09, h0, 36, 37, 38, 39)
    MAC4(w10, h0, 40, 41, 42, 43)  MAC4(w11, h0, 44, 45, 46, 47)
    MAC4(w12, h0, 48, 49, 50, 51)  MAC4(w13, h0, 52, 53, 54, 55)
    MAC4(w14, h0, 56, 57, 58, 59)  MAC4(w15, h0, 60, 61, 62, 63)
    MAC4(w16, h1,  0,  1,  2,  3)  MAC4(w17, h1,  4,  5,  6,  7)
    MAC4(w18, h1,  8,  9, 10, 11)  MAC4(w19, h1, 12, 13, 14, 15)
    MAC4(w20, h1, 16, 17, 18, 19)  MAC4(w21, h1, 20, 21, 22, 23)
    MAC4(w22, h1, 24, 25, 26, 27)  MAC4(w23, h1, 28, 29, 30, 31)
    MAC4(w24, h1, 32, 33, 34, 35)  MAC4(w25, h1, 36, 37, 38, 39)
    MAC4(w26, h1, 40, 41, 42, 43)  MAC4(w27, h1, 44, 45, 46, 47)
    MAC4(w28, h1, 48, 49, 50, 51)  MAC4(w29, h1, 52, 53, 54, 55)
    MAC4(w30, h1, 56, 57, 58, 59)  MAC4(w31, h1, 60, 61, 62, 63)
    ga[t] = acc_a + acc_b;
    __syncthreads();
    if (t < 128) {
      float iv = 1.f / (1.f + expf(-ga[t]));
      float fv = 1.f / (1.f + expf(-ga[t + 128]));
      float gv = tanhf(ga[t + 256]);
      float ov = 1.f / (1.f + expf(-ga[t + 384]));
      c = fv * c + iv * gv;
      float h = ov * tanhf(c);
      hbuf[t] = h;
      lout[((size_t)b * 50 + step) * 128 + t] = h;
    }
    __syncthreads();
  }
}

// ---------------------------------------------------------------------------
// Prediction head: p1 = lout . (pred_w^T tc) + tc . pred_b
// ---------------------------------------------------------------------------
__global__ __launch_bounds__(128) void k_pred(const float* __restrict__ lout,
    const float* __restrict__ pred_w, const float* __restrict__ pred_b,
    const float* __restrict__ tc, const float* __restrict__ result,
    float* __restrict__ out, float* __restrict__ fpbuf, float* __restrict__ mbuf) {
  int row = blockIdx.x; int k = threadIdx.x;
  __shared__ float tcs[101];
  __shared__ float r1[128], r2[128], r3[128];
  if (k < 101) tcs[k] = tc[(size_t)row * 101 + k];
  __syncthreads();
  float lk = lout[(size_t)row * 128 + k];
  float acc = 0.f;
  for (int c = 0; c < 101; c++) acc += tcs[c] * pred_w[c * 128 + k];
  float v = acc * lk;
  float pb = (k < 101) ? tcs[k] * pred_b[k] : 0.f;
  float nc = (k < 101) ? tcs[k] : 0.f;
  r1[k] = v; r2[k] = pb; r3[k] = nc;
  __syncthreads();
  for (int st = 64; st > 0; st >>= 1) {
    if (k < st) { r1[k] += r1[k + st]; r2[k] += r2[k + st]; r3[k] += r3[k + st]; }
    __syncthreads();
  }
  if (k == 0) {
    float ncon = r3[0];
    float m = (ncon > 0.f) ? 1.f : 0.f;
    float fp = (r1[0] + r2[0]) / fmaxf(ncon, 1.f);
    fpbuf[row] = fp; mbuf[row] = m;
    out[1 + row] = m / (1.f + expf(-fp));
    out[1 + NROW + row] = result[row] * m;
  }
}

// ---------------------------------------------------------------------------
// Loss reduction (single block, deterministic tree reduce)
// ---------------------------------------------------------------------------
__global__ __launch_bounds__(256) void k_loss(const float* __restrict__ fpbuf,
    const float* __restrict__ mbuf, const float* __restrict__ result,
    float* __restrict__ out) {
  __shared__ float sb[256], sm[256];
  int k = threadIdx.x;
  float ab = 0.f, am = 0.f;
  for (int r = k; r < NROW; r += 256) {
    float fp = fpbuf[r], m = mbuf[r], res = result[r];
    float bce = fmaxf(fp, 0.f) - fp * res + log1pf(expf(-fabsf(fp)));
    ab += bce * m; am += m;
  }
  sb[k] = ab; sm[k] = am;
  __syncthreads();
  for (int st = 128; st > 0; st >>= 1) {
    if (k < st) { sb[k] += sb[k + st]; sm[k] += sm[k + st]; }
    __syncthreads();
  }
  if (k == 0) out[0] = sb[0] / fmaxf(sm[0], 1.f);
}

// ---------------------------------------------------------------------------
extern "C" void kernel_launch(void* const* d_in, const int* in_sizes, int n_in,
                              void* d_out, int out_size, void* d_ws, size_t ws_size,
                              hipStream_t stream) {
  (void)in_sizes; (void)n_in; (void)out_size; (void)ws_size;
  const int*   ast      = (const int*)  d_in[2];
  const float* target_c = (const float*)d_in[3];
  const float* c_embed  = (const float*)d_in[4];
  const float* cur_res  = (const float*)d_in[5];
  const float* result   = (const float*)d_in[6];
  const float* emb      = (const float*)d_in[7];
  const float* Wc_w     = (const float*)d_in[8];
  const float* Wc_b     = (const float*)d_in[9];
  const float* gru_WxF  = (const float*)d_in[10];
  const float* gru_WhF  = (const float*)d_in[11];
  const float* gru_bxF  = (const float*)d_in[12];
  const float* gru_bhF  = (const float*)d_in[13];
  const float* gru_WxB  = (const float*)d_in[14];
  const float* gru_WhB  = (const float*)d_in[15];
  const float* gru_bxB  = (const float*)d_in[16];
  const float* gru_bhB  = (const float*)d_in[17];
  const float* lstm_Wx  = (const float*)d_in[18];
  const float* lstm_Wh  = (const float*)d_in[19];
  const float* lstm_bx  = (const float*)d_in[20];
  const float* lstm_bh  = (const float*)d_in[21];
  const float* pred_w   = (const float*)d_in[22];
  const float* pred_b   = (const float*)d_in[23];
  float* out = (float*)d_out;

  float* W = (float*)d_ws;
  float* Ep     = W;                 // 6,400,000 (VOCAB*128)
  float* xe_all = W;                 // alias: 25600*192 = 4,915,200 <= Ep size
  float* x      = W + 6400000;       // 3,276,800
  float* Wall   = W + 9676800;       // 24,576
  float* ball   = W + 9701376;       // 192
  float* Wxp    = W + 9701568;       // 98,304 (512 x 192)
  float* code   = W + 9799872;       // 102,400
  float* lin    = W + 9902272;       // 307,200 (1600 x 192)
  float* xeL    = W + 10209472;      // 819,200
  float* lout   = W + 11028672;      // 204,800
  float* fpbuf  = W + 11233472;      // 1,600
  float* mbuf   = W + 11235072;      // 1,600  (end: 11,236,672 floats ~45MB)

  // 1. E' = emb @ Wc_w^T   (vocab-level projection)
  sgemm_nt<<<dim3(1, 782), 256, 0, stream>>>(emb, Wc_w, nullptr, Ep, VOCAB, 128, 128);
  // 2. weight prep (incl. lstm_Wx pad 167->192)
  k_prep<<<384, 256, 0, stream>>>(gru_WxF, gru_WxB, gru_bxF, gru_bxB, lstm_Wx,
                                  Wall, ball, Wxp);
  // 3. tree gather/sum/max -> x (25600 x 128)
  k_tree<<<NTREE / 2, 256, 0, stream>>>(ast, Ep, Wc_b, x);
  // 4. xe_all = x @ Wall^T + ball  (25600 x 192)  [aliases Ep region]
  sgemm_nt<<<dim3(2, 400), 256, 0, stream>>>(x, Wall, ball, xe_all, NTREE, 192, 128);
  // 5. GRU recurrence + time max -> code (1600 x 64)
  k_gru<<<NROW * 2, 128, 0, stream>>>(xe_all, gru_WhF, gru_WhB, gru_bhF, gru_bhB, code);
  // 6. lin build (1600 x 192, zero-padded)
  k_lin<<<(NROW * LIN_P + 255) / 256, 256, 0, stream>>>(c_embed, code, cur_res, lin);
  // 7. xeL = lin @ Wxp^T + lstm_bx (1600 x 512, K=192 vector path)
  sgemm_nt<<<dim3(4, 25), 256, 0, stream>>>(lin, Wxp, lstm_bx, xeL, NROW, 512, LIN_P);
  // 8. LSTM recurrence -> lout (1600 x 128)  [named-var register weights]
  k_lstm<<<BS, 512, 0, stream>>>(xeL, lstm_Wh, lstm_bh, lout);
  // 9. prediction head -> out[1..], fpbuf, mbuf
  k_pred<<<NROW, 128, 0, stream>>>(lout, pred_w, pred_b, target_c, result,
                                   out, fpbuf, mbuf);
  // 10. loss -> out[0]
  k_loss<<<1, 256, 0, stream>>>(fpbuf, mbuf, result, out);
}

// Round 9
// 233.027 us; speedup vs baseline: 1.1031x; 1.0049x over previous
//
#include <hip/hip_runtime.h>
#include <hip/hip_bf16.h>
#include <math.h>

// Problem constants
#define BS 32
#define SEQ 50
#define ML 16
#define NN 15
#define NTREE (BS*SEQ*ML)     // 25600
#define NROW (BS*SEQ)         // 1600
#define VOCAB 50000
#define EMB 128
#define ENC 128
#define GH 32
#define NC 100
#define LH 128
#define LIN_D 167             // 101 + 64 + 2
#define LIN_P 192             // padded K for the xeL GEMM (vector path)

typedef float f32x4 __attribute__((ext_vector_type(4)));

// ---------------------------------------------------------------------------
// fp32 GEMM: C[M][N] = A[M][K] @ B[N][K]^T (+ bias[N])
// BM=64 x BN=128 tile, BK=32, 256 threads, 4x8 per thread.
// ---------------------------------------------------------------------------
__global__ __launch_bounds__(256) void sgemm_nt(const float* __restrict__ A,
    const float* __restrict__ B, const float* __restrict__ bias,
    float* __restrict__ C, int M, int N, int K) {
  __shared__ float As[32][68];    // [k][m]
  __shared__ float Bs[32][132];   // [k][n]
  const int bm = blockIdx.y * 64, bn = blockIdx.x * 128;
  const int tid = threadIdx.x;
  const int tm = (tid >> 4) << 2;   // 0..60
  const int tn = (tid & 15) << 3;   // 0..120
  const int srow = tid >> 3;        // 0..31
  const int q4 = (tid & 7) << 2;    // 0,4,..,28
  const bool vec_ok = ((K & 3) == 0);

  float acc[4][8];
  #pragma unroll
  for (int i = 0; i < 4; i++)
    #pragma unroll
    for (int j = 0; j < 8; j++) acc[i][j] = 0.f;

  for (int k0 = 0; k0 < K; k0 += 32) {
    if (vec_ok && (k0 + 32 <= K)) {
      #pragma unroll
      for (int h = 0; h < 2; h++) {
        int gm = bm + srow + h * 32;
        int rm = (gm < M) ? gm : (M - 1);
        float4 av = *(const float4*)&A[(size_t)rm * K + k0 + q4];
        As[q4 + 0][srow + h * 32] = av.x;
        As[q4 + 1][srow + h * 32] = av.y;
        As[q4 + 2][srow + h * 32] = av.z;
        As[q4 + 3][srow + h * 32] = av.w;
      }
      #pragma unroll
      for (int h = 0; h < 4; h++) {
        int gn = bn + srow + h * 32;
        float4 bv = make_float4(0.f, 0.f, 0.f, 0.f);
        if (gn < N) bv = *(const float4*)&B[(size_t)gn * K + k0 + q4];
        Bs[q4 + 0][srow + h * 32] = bv.x;
        Bs[q4 + 1][srow + h * 32] = bv.y;
        Bs[q4 + 2][srow + h * 32] = bv.z;
        Bs[q4 + 3][srow + h * 32] = bv.w;
      }
    } else {
      #pragma unroll
      for (int h = 0; h < 2; h++) {
        int gm = bm + srow + h * 32;
        int rm = (gm < M) ? gm : (M - 1);
        #pragma unroll
        for (int j = 0; j < 4; j++) {
          int gk = k0 + q4 + j;
          As[q4 + j][srow + h * 32] = (gk < K) ? A[(size_t)rm * K + gk] : 0.f;
        }
      }
      #pragma unroll
      for (int h = 0; h < 4; h++) {
        int gn = bn + srow + h * 32;
        #pragma unroll
        for (int j = 0; j < 4; j++) {
          int gk = k0 + q4 + j;
          Bs[q4 + j][srow + h * 32] =
              (gn < N && gk < K) ? B[(size_t)gn * K + gk] : 0.f;
        }
      }
    }
    __syncthreads();
    #pragma unroll
    for (int kk = 0; kk < 32; kk++) {
      float4 a4 = *(const float4*)&As[kk][tm];
      float4 b0 = *(const float4*)&Bs[kk][tn];
      float4 b1 = *(const float4*)&Bs[kk][tn + 4];
      float a[4] = {a4.x, a4.y, a4.z, a4.w};
      float b[8] = {b0.x, b0.y, b0.z, b0.w, b1.x, b1.y, b1.z, b1.w};
      #pragma unroll
      for (int i = 0; i < 4; i++)
        #pragma unroll
        for (int j = 0; j < 8; j++) acc[i][j] += a[i] * b[j];
    }
    __syncthreads();
  }

  float bb[8];
  #pragma unroll
  for (int j = 0; j < 8; j++) {
    int gn = bn + tn + j;
    bb[j] = (bias && gn < N) ? bias[gn] : 0.f;
  }
  if (bn + tn < N) {
    #pragma unroll
    for (int i = 0; i < 4; i++) {
      int gm = bm + tm + i;
      if (gm >= M) continue;
      float4 v0 = make_float4(acc[i][0] + bb[0], acc[i][1] + bb[1],
                              acc[i][2] + bb[2], acc[i][3] + bb[3]);
      float4 v1 = make_float4(acc[i][4] + bb[4], acc[i][5] + bb[5],
                              acc[i][6] + bb[6], acc[i][7] + bb[7]);
      *(float4*)&C[(size_t)gm * N + bn + tn] = v0;
      *(float4*)&C[(size_t)gm * N + bn + tn + 4] = v1;
    }
  }
}

// ---------------------------------------------------------------------------
// Prep: Wall = [WxF; WxB] (192x128), ball = [bxF; bxB],
//       Wxp = lstm_Wx zero-padded K 167 -> 192 (512 x 192)
// ---------------------------------------------------------------------------
__global__ __launch_bounds__(256) void k_prep(const float* __restrict__ WxF,
    const float* __restrict__ WxB, const float* __restrict__ bxF,
    const float* __restrict__ bxB, const float* __restrict__ lstm_Wx,
    float* __restrict__ Wall, float* __restrict__ ball,
    float* __restrict__ Wxp) {
  int i = blockIdx.x * 256 + threadIdx.x;
  if (i < 96 * 128) Wall[i] = WxF[i];
  else if (i < 192 * 128) Wall[i] = WxB[i - 96 * 128];
  if (i < 96) ball[i] = bxF[i];
  else if (i < 192) ball[i] = bxB[i - 96];
  if (i < 512 * LIN_P) {
    int n = i / LIN_P, k = i - n * LIN_P;
    Wxp[i] = (k < LIN_D) ? lstm_Wx[n * LIN_D + k] : 0.f;
  }
}

// ---------------------------------------------------------------------------
// Tree: gather 15 rows of E', bottom-up subtree sums, node max. 2 trees/block.
// ---------------------------------------------------------------------------
__global__ __launch_bounds__(256) void k_tree(const int* __restrict__ ast,
    const float* __restrict__ Ep, const float* __restrict__ Wc_b,
    float* __restrict__ x) {
  int lt = threadIdx.x >> 7;      // 0/1
  int d  = threadIdx.x & 127;
  int tree = blockIdx.x * 2 + lt;
  __shared__ int toks[2][15];
  if (d < 15) toks[lt][d] = ast[(size_t)tree * 15 + d];
  __syncthreads();
  float e[15];
  #pragma unroll
  for (int n = 0; n < 15; n++) e[n] = Ep[(size_t)toks[lt][n] * 128 + d];
  float b = Wc_b[d];
  float s3 = e[3] + e[7] + e[8],  s4 = e[4] + e[9] + e[10];
  float s5 = e[5] + e[11] + e[12], s6 = e[6] + e[13] + e[14];
  float s1 = e[1] + s3 + s4, s2 = e[2] + s5 + s6;
  float s0 = e[0] + s1 + s2;
  float ml = fmaxf(fmaxf(fmaxf(e[7], e[8]), fmaxf(e[9], e[10])),
                   fmaxf(fmaxf(e[11], e[12]), fmaxf(e[13], e[14]))) + b;
  float mm = fmaxf(fmaxf(s3, s4), fmaxf(s5, s6)) + 3.f * b;
  float mt = fmaxf(s1, s2) + 7.f * b;
  float m = fmaxf(fmaxf(ml, mm), fmaxf(mt, s0 + 15.f * b));
  x[(size_t)tree * 128 + d] = m;
}

// ---------------------------------------------------------------------------
// GRU recurrence, one block per (sequence, direction). Hidden=32, gates=96.
// ---------------------------------------------------------------------------
__global__ __launch_bounds__(128) void k_gru(const float* __restrict__ xe_all,
    const float* __restrict__ WhF, const float* __restrict__ WhB,
    const float* __restrict__ bhF, const float* __restrict__ bhB,
    float* __restrict__ code) {
  int bsq = blockIdx.x >> 1, dir = blockIdx.x & 1;
  int g = threadIdx.x;
  __shared__ float whs[96 * 32];
  __shared__ float h_lds[32];
  __shared__ float rz[64];
  __shared__ float nn[32];
  const float* Wh = dir ? WhB : WhF;
  const float* bh = dir ? bhB : bhF;
  for (int i = g; i < 96 * 32; i += 128) whs[i] = Wh[i];
  if (g < 32) h_lds[g] = 0.f;
  __syncthreads();
  float w[32]; float bhv = 0.f, mxv = -1e30f;
  if (g < 96) {
    #pragma unroll
    for (int j = 0; j < 32; j++) w[j] = whs[g * 32 + j];
    bhv = bh[g];
  }
  for (int s = 0; s < 16; s++) {
    int t = dir ? (15 - s) : s;
    const float* xe = xe_all + ((size_t)(bsq * 16 + t)) * 192 + dir * 96;
    float gh = bhv, xv = 0.f;
    if (g < 96) {
      xv = xe[g];
      #pragma unroll
      for (int j = 0; j < 32; j++) gh += w[j] * h_lds[j];
    }
    if (g < 64) rz[g] = 1.f / (1.f + expf(-(xv + gh)));
    __syncthreads();
    if (g >= 64 && g < 96) nn[g - 64] = tanhf(xv + rz[g - 64] * gh);
    __syncthreads();
    if (g < 32) {
      float z = rz[g + 32];
      float hn = (1.f - z) * nn[g] + z * h_lds[g];
      mxv = fmaxf(mxv, hn);
      h_lds[g] = hn;
    }
    __syncthreads();
  }
  if (g < 32) code[(size_t)bsq * 64 + dir * 32 + g] = mxv;
}

// ---------------------------------------------------------------------------
// Build lin = [c_embed(101) | code(64) | cur_result(2) | 0-pad to 192]
// ---------------------------------------------------------------------------
__global__ __launch_bounds__(256) void k_lin(const float* __restrict__ c_embed,
    const float* __restrict__ code, const float* __restrict__ cur,
    float* __restrict__ lin) {
  int i = blockIdx.x * 256 + threadIdx.x;
  if (i >= NROW * LIN_P) return;
  int row = i / LIN_P, j = i - row * LIN_P;
  float v;
  if (j < 101) v = c_embed[row * 101 + j];
  else if (j < 165) v = code[row * 64 + (j - 101)];
  else if (j < 167) v = cur[row * 2 + (j - 165)];
  else v = 0.f;
  lin[i] = v;
}

// ---------------------------------------------------------------------------
// LSTM v8: 32 blocks x 512 threads. Thread t owns gate row t in 32 named
// f32x4 (asm-pinned loads). NO LIBM CALLS anywhere in the kernel: sigmoid/
// tanh via raw v_exp_f32 (2^x) + v_rcp_f32 builtins. If __ocml_* stayed as
// real calls, the ABI forced caller-saved spill of all weight VGPRs around
// them (hoisted out of the loop = the persistent whole-array spill seen in
// R2-R8: VGPR_Count 48..144 < payload every time).
// Gate activations computed by all 512 threads pre-barrier; serial phase is
// just c/h update + one tanh.
// ---------------------------------------------------------------------------
#define RL(v, l) __int_as_float(__builtin_amdgcn_readlane(__float_as_int(v), (l)))

#define LOG2E 1.4426950408889634f

__device__ __forceinline__ float fsig(float x) {
  return __builtin_amdgcn_rcpf(1.f + __builtin_amdgcn_exp2f(-LOG2E * x));
}
__device__ __forceinline__ float ftanh(float x) {
  return 2.f * __builtin_amdgcn_rcpf(
             1.f + __builtin_amdgcn_exp2f(-2.f * LOG2E * x)) - 1.f;
}

#define LOADW(W, OFF) \
  asm volatile("global_load_dwordx4 %0, %1, off offset:" #OFF \
               : "=v"(W) : "v"(base));

#define MAC4(W, H, L0, L1, L2, L3) \
  acc_a += RL(H, L0) * W.x; acc_b += RL(H, L1) * W.y; \
  acc_a += RL(H, L2) * W.z; acc_b += RL(H, L3) * W.w;

__global__ __attribute__((amdgpu_flat_work_group_size(512, 512),
                          amdgpu_waves_per_eu(2, 2)))
void k_lstm(const float* __restrict__ xeL,
    const float* __restrict__ Wh, const float* __restrict__ bh,
    float* __restrict__ lout) {
  int b = blockIdx.x; int t = threadIdx.x;
  int lane = t & 63;
  __shared__ float hbuf[128];
  __shared__ float ga[512];
  f32x4 w00, w01, w02, w03, w04, w05, w06, w07;
  f32x4 w08, w09, w10, w11, w12, w13, w14, w15;
  f32x4 w16, w17, w18, w19, w20, w21, w22, w23;
  f32x4 w24, w25, w26, w27, w28, w29, w30, w31;
  const float* base = Wh + (size_t)t * 128;
  LOADW(w00,   0) LOADW(w01,  16) LOADW(w02,  32) LOADW(w03,  48)
  LOADW(w04,  64) LOADW(w05,  80) LOADW(w06,  96) LOADW(w07, 112)
  LOADW(w08, 128) LOADW(w09, 144) LOADW(w10, 160) LOADW(w11, 176)
  LOADW(w12, 192) LOADW(w13, 208) LOADW(w14, 224) LOADW(w15, 240)
  LOADW(w16, 256) LOADW(w17, 272) LOADW(w18, 288) LOADW(w19, 304)
  LOADW(w20, 320) LOADW(w21, 336) LOADW(w22, 352) LOADW(w23, 368)
  LOADW(w24, 384) LOADW(w25, 400) LOADW(w26, 416) LOADW(w27, 432)
  LOADW(w28, 448) LOADW(w29, 464) LOADW(w30, 480) LOADW(w31, 496)
  asm volatile("s_waitcnt vmcnt(0)" ::: "memory");
  __builtin_amdgcn_sched_barrier(0);

  float bhv = bh[t];
  float c = 0.f;
  const bool is_tanh_gate = ((t >> 7) == 2);   // gates 256..383 = g-gate
  if (t < 128) hbuf[t] = 0.f;
  const float* xrow = xeL + (size_t)b * 50 * 512;
  float xe = xrow[t];                 // step-0 prefetch
  __syncthreads();
  for (int step = 0; step < 50; step++) {
    float h0 = hbuf[lane];
    float h1 = hbuf[64 + lane];
    float acc_a = xe + bhv, acc_b = 0.f;
    if (step < 49) xe = xrow[(size_t)(step + 1) * 512 + t];
    MAC4(w00, h0,  0,  1,  2,  3)  MAC4(w01, h0,  4,  5,  6,  7)
    MAC4(w02, h0,  8,  9, 10, 11)  MAC4(w03, h0, 12, 13, 14, 15)
    MAC4(w04, h0, 16, 17, 18, 19)  MAC4(w05, h0, 20, 21, 22, 23)
    MAC4(w06, h0, 24, 25, 26, 27)  MAC4(w07, h0, 28, 29, 30, 31)
    MAC4(w08, h0, 32, 33, 34, 35)  MAC4(w09, h0, 36, 37, 38, 39)
    MAC4(w10, h0, 40, 41, 42, 43)  MAC4(w11, h0, 44, 45, 46, 47)
    MAC4(w12, h0, 48, 49, 50, 51)  MAC4(w13, h0, 52, 53, 54, 55)
    MAC4(w14, h0, 56, 57, 58, 59)  MAC4(w15, h0, 60, 61, 62, 63)
    MAC4(w16, h1,  0,  1,  2,  3)  MAC4(w17, h1,  4,  5,  6,  7)
    MAC4(w18, h1,  8,  9, 10, 11)  MAC4(w19, h1, 12, 13, 14, 15)
    MAC4(w20, h1, 16, 17, 18, 19)  MAC4(w21, h1, 20, 21, 22, 23)
    MAC4(w22, h1, 24, 25, 26, 27)  MAC4(w23, h1, 28, 29, 30, 31)
    MAC4(w24, h1, 32, 33, 34, 35)  MAC4(w25, h1, 36, 37, 38, 39)
    MAC4(w26, h1, 40, 41, 42, 43)  MAC4(w27, h1, 44, 45, 46, 47)
    MAC4(w28, h1, 48, 49, 50, 51)  MAC4(w29, h1, 52, 53, 54, 55)
    MAC4(w30, h1, 56, 57, 58, 59)  MAC4(w31, h1, 60, 61, 62, 63)
    float gav = acc_a + acc_b;
    ga[t] = is_tanh_gate ? ftanh(gav) : fsig(gav);
    __syncthreads();
    if (t < 128) {
      c = ga[t + 128] * c + ga[t] * ga[t + 256];
      float h = ga[t + 384] * ftanh(c);
      hbuf[t] = h;
      lout[((size_t)b * 50 + step) * 128 + t] = h;
    }
    __syncthreads();
  }
}

// ---------------------------------------------------------------------------
// Prediction head: p1 = lout . (pred_w^T tc) + tc . pred_b
// ---------------------------------------------------------------------------
__global__ __launch_bounds__(128) void k_pred(const float* __restrict__ lout,
    const float* __restrict__ pred_w, const float* __restrict__ pred_b,
    const float* __restrict__ tc, const float* __restrict__ result,
    float* __restrict__ out, float* __restrict__ fpbuf, float* __restrict__ mbuf) {
  int row = blockIdx.x; int k = threadIdx.x;
  __shared__ float tcs[101];
  __shared__ float r1[128], r2[128], r3[128];
  if (k < 101) tcs[k] = tc[(size_t)row * 101 + k];
  __syncthreads();
  float lk = lout[(size_t)row * 128 + k];
  float acc = 0.f;
  for (int c = 0; c < 101; c++) acc += tcs[c] * pred_w[c * 128 + k];
  float v = acc * lk;
  float pb = (k < 101) ? tcs[k] * pred_b[k] : 0.f;
  float nc = (k < 101) ? tcs[k] : 0.f;
  r1[k] = v; r2[k] = pb; r3[k] = nc;
  __syncthreads();
  for (int st = 64; st > 0; st >>= 1) {
    if (k < st) { r1[k] += r1[k + st]; r2[k] += r2[k + st]; r3[k] += r3[k + st]; }
    __syncthreads();
  }
  if (k == 0) {
    float ncon = r3[0];
    float m = (ncon > 0.f) ? 1.f : 0.f;
    float fp = (r1[0] + r2[0]) / fmaxf(ncon, 1.f);
    fpbuf[row] = fp; mbuf[row] = m;
    out[1 + row] = m / (1.f + expf(-fp));
    out[1 + NROW + row] = result[row] * m;
  }
}

// ---------------------------------------------------------------------------
// Loss reduction (single block, deterministic tree reduce)
// ---------------------------------------------------------------------------
__global__ __launch_bounds__(256) void k_loss(const float* __restrict__ fpbuf,
    const float* __restrict__ mbuf, const float* __restrict__ result,
    float* __restrict__ out) {
  __shared__ float sb[256], sm[256];
  int k = threadIdx.x;
  float ab = 0.f, am = 0.f;
  for (int r = k; r < NROW; r += 256) {
    float fp = fpbuf[r], m = mbuf[r], res = result[r];
    float bce = fmaxf(fp, 0.f) - fp * res + log1pf(expf(-fabsf(fp)));
    ab += bce * m; am += m;
  }
  sb[k] = ab; sm[k] = am;
  __syncthreads();
  for (int st = 128; st > 0; st >>= 1) {
    if (k < st) { sb[k] += sb[k + st]; sm[k] += sm[k + st]; }
    __syncthreads();
  }
  if (k == 0) out[0] = sb[0] / fmaxf(sm[0], 1.f);
}

// ---------------------------------------------------------------------------
extern "C" void kernel_launch(void* const* d_in, const int* in_sizes, int n_in,
                              void* d_out, int out_size, void* d_ws, size_t ws_size,
                              hipStream_t stream) {
  (void)in_sizes; (void)n_in; (void)out_size; (void)ws_size;
  const int*   ast      = (const int*)  d_in[2];
  const float* target_c = (const float*)d_in[3];
  const float* c_embed  = (const float*)d_in[4];
  const float* cur_res  = (const float*)d_in[5];
  const float* result   = (const float*)d_in[6];
  const float* emb      = (const float*)d_in[7];
  const float* Wc_w     = (const float*)d_in[8];
  const float* Wc_b     = (const float*)d_in[9];
  const float* gru_WxF  = (const float*)d_in[10];
  const float* gru_WhF  = (const float*)d_in[11];
  const float* gru_bxF  = (const float*)d_in[12];
  const float* gru_bhF  = (const float*)d_in[13];
  const float* gru_WxB  = (const float*)d_in[14];
  const float* gru_WhB  = (const float*)d_in[15];
  const float* gru_bxB  = (const float*)d_in[16];
  const float* gru_bhB  = (const float*)d_in[17];
  const float* lstm_Wx  = (const float*)d_in[18];
  const float* lstm_Wh  = (const float*)d_in[19];
  const float* lstm_bx  = (const float*)d_in[20];
  const float* lstm_bh  = (const float*)d_in[21];
  const float* pred_w   = (const float*)d_in[22];
  const float* pred_b   = (const float*)d_in[23];
  float* out = (float*)d_out;

  float* W = (float*)d_ws;
  float* Ep     = W;                 // 6,400,000 (VOCAB*128)
  float* xe_all = W;                 // alias: 25600*192 = 4,915,200 <= Ep size
  float* x      = W + 6400000;       // 3,276,800
  float* Wall   = W + 9676800;       // 24,576
  float* ball   = W + 9701376;       // 192
  float* Wxp    = W + 9701568;       // 98,304 (512 x 192)
  float* code   = W + 9799872;       // 102,400
  float* lin    = W + 9902272;       // 307,200 (1600 x 192)
  float* xeL    = W + 10209472;      // 819,200
  float* lout   = W + 11028672;      // 204,800
  float* fpbuf  = W + 11233472;      // 1,600
  float* mbuf   = W + 11235072;      // 1,600  (end: 11,236,672 floats ~45MB)

  // 1. E' = emb @ Wc_w^T   (vocab-level projection)
  sgemm_nt<<<dim3(1, 782), 256, 0, stream>>>(emb, Wc_w, nullptr, Ep, VOCAB, 128, 128);
  // 2. weight prep (incl. lstm_Wx pad 167->192)
  k_prep<<<384, 256, 0, stream>>>(gru_WxF, gru_WxB, gru_bxF, gru_bxB, lstm_Wx,
                                  Wall, ball, Wxp);
  // 3. tree gather/sum/max -> x (25600 x 128)
  k_tree<<<NTREE / 2, 256, 0, stream>>>(ast, Ep, Wc_b, x);
  // 4. xe_all = x @ Wall^T + ball  (25600 x 192)  [aliases Ep region]
  sgemm_nt<<<dim3(2, 400), 256, 0, stream>>>(x, Wall, ball, xe_all, NTREE, 192, 128);
  // 5. GRU recurrence + time max -> code (1600 x 64)
  k_gru<<<NROW * 2, 128, 0, stream>>>(xe_all, gru_WhF, gru_WhB, gru_bhF, gru_bhB, code);
  // 6. lin build (1600 x 192, zero-padded)
  k_lin<<<(NROW * LIN_P + 255) / 256, 256, 0, stream>>>(c_embed, code, cur_res, lin);
  // 7. xeL = lin @ Wxp^T + lstm_bx (1600 x 512, K=192 vector path)
  sgemm_nt<<<dim3(4, 25), 256, 0, stream>>>(lin, Wxp, lstm_bx, xeL, NROW, 512, LIN_P);
  // 8. LSTM recurrence -> lout (1600 x 128)  [no libm calls: exp2/rcp builtins]
  k_lstm<<<BS, 512, 0, stream>>>(xeL, lstm_Wh, lstm_bh, lout);
  // 9. prediction head -> out[1..], fpbuf, mbuf
  k_pred<<<NROW, 128, 0, stream>>>(lout, pred_w, pred_b, target_c, result,
                                   out, fpbuf, mbuf);
  // 10. loss -> out[0]
  k_loss<<<1, 256, 0, stream>>>(fpbuf, mbuf, result, out);
}